// Round 1
// baseline (135.886 us; speedup 1.0000x reference)
//
#include <hip/hip_runtime.h>
#include <math.h>

constexpr int NQ  = 12;
constexpr int NS  = 1 << NQ;   // 4096 states
constexpr int NL  = 4;
constexpr int BLK = 256;
constexpr float PI_F = 3.14159265358979323846f;

// Apply a general 2x2 unitary to qubit at bit position p (LSB-indexed).
// Each thread owns disjoint (i0,i1) pairs -> no intra-gate hazard.
// Caller relies on the trailing __syncthreads().
__device__ __forceinline__ void gate1q(float2* psi,
                                       float2 U00, float2 U01,
                                       float2 U10, float2 U11,
                                       int p, int tid)
{
    const int stride = 1 << p;
    #pragma unroll
    for (int it = 0; it < (NS / 2) / BLK; ++it) {
        int k  = tid + it * BLK;
        int i0 = ((k >> p) << (p + 1)) | (k & (stride - 1));
        int i1 = i0 | stride;
        float2 a = psi[i0];
        float2 b = psi[i1];
        float2 r0, r1;
        r0.x = U00.x * a.x - U00.y * a.y + U01.x * b.x - U01.y * b.y;
        r0.y = U00.x * a.y + U00.y * a.x + U01.x * b.y + U01.y * b.x;
        r1.x = U10.x * a.x - U10.y * a.y + U11.x * b.x - U11.y * b.y;
        r1.y = U10.x * a.y + U10.y * a.x + U11.x * b.y + U11.y * b.x;
        psi[i0] = r0;
        psi[i1] = r1;
    }
    __syncthreads();
}

__device__ __forceinline__ int insert_zero(int v, int p) {
    return ((v >> p) << (p + 1)) | (v & ((1 << p) - 1));
}

// CNOT: control bit pc, target bit pt. Swap amps (c=1,t=0) <-> (c=1,t=1).
__device__ __forceinline__ void gate_cnot(float2* psi, int pc, int pt, int tid)
{
    const int pmin = pc < pt ? pc : pt;
    const int pmax = pc < pt ? pt : pc;
    #pragma unroll
    for (int it = 0; it < (NS / 4) / BLK; ++it) {
        int k = tid + it * BLK;
        int v = insert_zero(k, pmin);
        v     = insert_zero(v, pmax);
        int i0 = v | (1 << pc);        // control=1, target=0
        int i1 = i0 | (1 << pt);       // control=1, target=1
        float2 t0 = psi[i0];
        float2 t1 = psi[i1];
        psi[i0] = t1;
        psi[i1] = t0;
    }
    __syncthreads();
}

__global__ __launch_bounds__(BLK, 1)
void qsim_kernel(const float* __restrict__ x,    // (B, 12)
                 const float* __restrict__ w,    // (4, 12, 3)
                 const float* __restrict__ ent,  // (4, 12)
                 float* __restrict__ out)        // (B, 12)
{
    __shared__ float2 psi[NS];
    __shared__ float  red[4][NQ];

    const int tid = threadIdx.x;
    const int b   = blockIdx.x;

    // |00...0>
    #pragma unroll
    for (int it = 0; it < NS / BLK; ++it)
        psi[tid + it * BLK] = make_float2(0.f, 0.f);
    __syncthreads();
    if (tid == 0) psi[0] = make_float2(1.f, 0.f);
    __syncthreads();

    // -------- encoding: per qubit q, U = RZ(x^2*pi) * RY(x*pi) --------
    for (int q = 0; q < NQ; ++q) {
        float xv = x[b * NQ + q];
        float c, s;   sincosf(xv * PI_F * 0.5f, &s, &c);          // RY half-angle
        float zs, zc; sincosf(xv * xv * PI_F * 0.5f, &zs, &zc);   // RZ half-angle
        // U00 = c*(zc - i zs); U01 = -s*(zc - i zs)
        // U10 = s*(zc + i zs); U11 =  c*(zc + i zs)
        float2 U00 = { c * zc, -c * zs};
        float2 U01 = {-s * zc,  s * zs};
        float2 U10 = { s * zc,  s * zs};
        float2 U11 = { c * zc,  c * zs};
        gate1q(psi, U00, U01, U10, U11, NQ - 1 - q, tid);
    }

    // -------- layers --------
    for (int layer = 0; layer < NL; ++layer) {
        // Rot(phi, theta, omega) = RZ(om) RY(th) RZ(phi)
        for (int q = 0; q < NQ; ++q) {
            float phi = w[(layer * NQ + q) * 3 + 0];
            float th  = w[(layer * NQ + q) * 3 + 1];
            float om  = w[(layer * NQ + q) * 3 + 2];
            float c, s;   sincosf(th * 0.5f, &s, &c);
            float sa, ca; sincosf((phi + om) * 0.5f, &sa, &ca);
            float sm, cm; sincosf((phi - om) * 0.5f, &sm, &cm);
            // U00 = c e^{-i(phi+om)/2}; U01 = -s e^{+i(phi-om)/2}
            // U10 = s e^{-i(phi-om)/2}; U11 =  c e^{+i(phi+om)/2}
            float2 U00 = { c * ca, -c * sa};
            float2 U01 = {-s * cm, -s * sm};
            float2 U10 = { s * cm, -s * sm};
            float2 U11 = { c * ca,  c * sa};
            gate1q(psi, U00, U01, U10, U11, NQ - 1 - q, tid);
        }
        // ring CNOTs, each gated on entangler mask (grid-uniform branch)
        for (int q = 0; q < NQ; ++q) {
            if (ent[layer * NQ + q] > 0.5f) {
                int pc = NQ - 1 - q;
                int pt = NQ - 1 - ((q + 1) % NQ);
                gate_cnot(psi, pc, pt, tid);
            }
        }
    }

    // -------- measurement: <Z_q> = sum_s p(s) * (1 - 2*bit_q(s)) --------
    float acc[NQ];
    #pragma unroll
    for (int q = 0; q < NQ; ++q) acc[q] = 0.f;

    #pragma unroll
    for (int it = 0; it < NS / BLK; ++it) {
        int i = tid + it * BLK;
        float2 a = psi[i];
        float pr = a.x * a.x + a.y * a.y;
        #pragma unroll
        for (int q = 0; q < NQ; ++q)
            acc[q] += ((i >> (NQ - 1 - q)) & 1) ? -pr : pr;
    }

    // wave(64)-level butterfly, then cross-wave via LDS
    #pragma unroll
    for (int off = 32; off > 0; off >>= 1) {
        #pragma unroll
        for (int q = 0; q < NQ; ++q)
            acc[q] += __shfl_down(acc[q], off, 64);
    }
    const int lane = tid & 63;
    const int wv   = tid >> 6;
    if (lane == 0) {
        #pragma unroll
        for (int q = 0; q < NQ; ++q) red[wv][q] = acc[q];
    }
    __syncthreads();
    if (tid < NQ) {
        float s = red[0][tid] + red[1][tid] + red[2][tid] + red[3][tid];
        out[b * NQ + tid] = s;
    }
}

extern "C" void kernel_launch(void* const* d_in, const int* in_sizes, int n_in,
                              void* d_out, int out_size, void* d_ws, size_t ws_size,
                              hipStream_t stream) {
    const float* x   = (const float*)d_in[0];  // (B,12)
    const float* w   = (const float*)d_in[1];  // (4,12,3)
    const float* ent = (const float*)d_in[2];  // (4,12)
    float* out = (float*)d_out;
    const int B = in_sizes[0] / NQ;
    qsim_kernel<<<B, BLK, 0, stream>>>(x, w, ent, out);
}

// Round 2
// 86.268 us; speedup vs baseline: 1.5752x; 1.5752x over previous
//
#include <hip/hip_runtime.h>
#include <math.h>

constexpr int NQ  = 12;
constexpr int NS  = 1 << NQ;   // 4096 amplitudes
constexpr int NL  = 4;
constexpr int BLK = 256;
constexpr int R   = 16;        // amplitudes per thread (reg bits = amp bits 0..3)
constexpr float PI_F = 3.14159265358979323846f;

// amp index i = (tid << 4) | r
//   bits 0..3  : register index r
//   bits 4..9  : lane bits (tid bits 0..5)
//   bits 10..11: wave bits (tid bits 6..7)

typedef float2 c32;

__device__ __forceinline__ c32 cmul(c32 a, c32 b) {
    return make_float2(a.x * b.x - a.y * b.y, a.x * b.y + a.y * b.x);
}
// a*b + c
__device__ __forceinline__ c32 cmad(c32 a, c32 b, c32 c) {
    return make_float2(fmaf(a.x, b.x, fmaf(-a.y, b.y, c.x)),
                       fmaf(a.x, b.y, fmaf( a.y, b.x, c.y)));
}
__device__ __forceinline__ c32 shx(c32 v, int m) {
    return make_float2(__shfl_xor(v.x, m, 64), __shfl_xor(v.y, m, 64));
}

// ---- single-qubit gate, qubit bit lives in register index (P = 0..3) ----
template<int P>
__device__ __forceinline__ void gate_reg(c32* v, c32 U00, c32 U01, c32 U10, c32 U11) {
    #pragma unroll
    for (int r = 0; r < R; ++r)
        if (!(r & (1 << P))) {
            c32 a = v[r], b = v[r | (1 << P)];
            v[r]            = cmad(U01, b, cmul(U00, a));
            v[r | (1 << P)] = cmad(U11, b, cmul(U10, a));
        }
}

// ---- single-qubit gate, qubit bit is a lane bit (M = lane xor mask) ----
template<int M>
__device__ __forceinline__ void gate_lane(c32* v, int tid, c32 U00, c32 U01, c32 U10, c32 U11) {
    const bool hi = tid & M;
    const c32 Ud = hi ? U11 : U00;
    const c32 Uo = hi ? U10 : U01;
    #pragma unroll
    for (int r = 0; r < R; ++r) {
        c32 o = shx(v[r], M);
        v[r] = cmad(Uo, o, cmul(Ud, v[r]));
    }
}

// ---- single-qubit gate, qubit bit is a wave bit (XB = tid xor mask 64/128) ----
template<int XB>
__device__ __forceinline__ void gate_wave(c32* v, int tid, c32* xbuf,
                                          c32 U00, c32 U01, c32 U10, c32 U11) {
    #pragma unroll
    for (int r = 0; r < R; ++r) xbuf[r * BLK + tid] = v[r];
    __syncthreads();
    const int  pt = tid ^ XB;
    const bool hi = tid & XB;
    const c32 Ud = hi ? U11 : U00;
    const c32 Uo = hi ? U10 : U01;
    #pragma unroll
    for (int r = 0; r < R; ++r) {
        c32 o = xbuf[r * BLK + pt];
        v[r] = cmad(Uo, o, cmul(Ud, v[r]));
    }
    __syncthreads();
}

// ---- CNOT, control+target both lane bits ----
template<int CM, int TM>
__device__ __forceinline__ void cnot_ll(c32* v, int tid) {
    const bool c_ = tid & CM;
    #pragma unroll
    for (int r = 0; r < R; ++r) {
        c32 o = shx(v[r], TM);
        if (c_) v[r] = o;
    }
}

// ---- CNOT, control+target both register bits ----
template<int PC, int PT>
__device__ __forceinline__ void cnot_rr(c32* v) {
    #pragma unroll
    for (int r = 0; r < R; ++r)
        if ((r & (1 << PC)) && !(r & (1 << PT))) {
            c32 t = v[r]; v[r] = v[r ^ (1 << PT)]; v[r ^ (1 << PT)] = t;
        }
}

__global__ __launch_bounds__(BLK, 1)
void qsim_kernel(const float* __restrict__ x,    // (B,12)
                 const float* __restrict__ w,    // (4,12,3)
                 const float* __restrict__ ent,  // (4,12)
                 float* __restrict__ out)        // (B,12)
{
    __shared__ c32  xbuf[NS];           // 32 KB cross-wave exchange
    __shared__ c32  gmat[NL * NQ][4];   // Rot matrices (block-uniform)
    __shared__ c32  uenc[NQ][2];        // encoding per-qubit 2-vectors
    __shared__ int  entf[NL * NQ];
    __shared__ float redbuf[4 * NQ];

    const int tid = threadIdx.x;
    const int b   = blockIdx.x;

    // ---- precompute gate matrices (once per block) ----
    if (tid < NL * NQ) {
        float phi = w[tid * 3 + 0], th = w[tid * 3 + 1], om = w[tid * 3 + 2];
        float s, c;   sincosf(0.5f * th, &s, &c);
        float sa, ca; sincosf(0.5f * (phi + om), &sa, &ca);
        float sm, cm; sincosf(0.5f * (phi - om), &sm, &cm);
        gmat[tid][0] = make_float2( c * ca, -c * sa);
        gmat[tid][1] = make_float2(-s * cm, -s * sm);
        gmat[tid][2] = make_float2( s * cm, -s * sm);
        gmat[tid][3] = make_float2( c * ca,  c * sa);
        entf[tid] = ent[tid] > 0.5f;
    }
    if (tid >= 64 && tid < 64 + NQ) {
        int q = tid - 64;
        float xv = x[b * NQ + q];
        float s, c;   sincosf(0.5f * PI_F * xv, &s, &c);
        float zs, zc; sincosf(0.5f * PI_F * xv * xv, &zs, &zc);
        uenc[q][0] = make_float2(c * zc, -c * zs);   // amplitude of |0>
        uenc[q][1] = make_float2(s * zc,  s * zs);   // amplitude of |1>
    }
    __syncthreads();

    // ---- build encoded product state directly in registers ----
    // amp bit (11-q) of i; for q<=7 that's tid bit (7-q), for q>=8 it's r bit (11-q)
    c32 A = uenc[0][(tid >> 7) & 1];
    #pragma unroll
    for (int q = 1; q < 8; ++q) A = cmul(A, uenc[q][(tid >> (7 - q)) & 1]);
    c32 AP[4], PAB[4];
    #pragma unroll
    for (int j = 0; j < 4; ++j)
        AP[j] = cmul(A, cmul(uenc[8][j >> 1], uenc[9][j & 1]));
    #pragma unroll
    for (int k = 0; k < 4; ++k)
        PAB[k] = cmul(uenc[10][k >> 1], uenc[11][k & 1]);
    c32 v[R];
    #pragma unroll
    for (int r = 0; r < R; ++r) v[r] = cmul(AP[(r >> 2) & 3], PAB[r & 3]);

    // ---- layers ----
    #pragma unroll 1
    for (int layer = 0; layer < NL; ++layer) {
        const int gb = layer * NQ;
        // Rot gates: q -> amp bit p = 11-q
        { c32* g = gmat[gb + 0];  gate_wave<128>(v, tid, xbuf, g[0], g[1], g[2], g[3]); }
        { c32* g = gmat[gb + 1];  gate_wave< 64>(v, tid, xbuf, g[0], g[1], g[2], g[3]); }
        { c32* g = gmat[gb + 2];  gate_lane<32>(v, tid, g[0], g[1], g[2], g[3]); }
        { c32* g = gmat[gb + 3];  gate_lane<16>(v, tid, g[0], g[1], g[2], g[3]); }
        { c32* g = gmat[gb + 4];  gate_lane< 8>(v, tid, g[0], g[1], g[2], g[3]); }
        { c32* g = gmat[gb + 5];  gate_lane< 4>(v, tid, g[0], g[1], g[2], g[3]); }
        { c32* g = gmat[gb + 6];  gate_lane< 2>(v, tid, g[0], g[1], g[2], g[3]); }
        { c32* g = gmat[gb + 7];  gate_lane< 1>(v, tid, g[0], g[1], g[2], g[3]); }
        { c32* g = gmat[gb + 8];  gate_reg<3>(v, g[0], g[1], g[2], g[3]); }
        { c32* g = gmat[gb + 9];  gate_reg<2>(v, g[0], g[1], g[2], g[3]); }
        { c32* g = gmat[gb + 10]; gate_reg<1>(v, g[0], g[1], g[2], g[3]); }
        { c32* g = gmat[gb + 11]; gate_reg<0>(v, g[0], g[1], g[2], g[3]); }

        // ring CNOTs, q ascending; (pc,pt) = (11-q, 10-q), wrap (0,11)
        if (entf[gb + 0]) {          // (11,10): wave,wave — waves 2,3 swap
            #pragma unroll
            for (int r = 0; r < R; ++r) xbuf[r * BLK + tid] = v[r];
            __syncthreads();
            if (tid & 128) {
                const int pt = tid ^ 64;
                #pragma unroll
                for (int r = 0; r < R; ++r) v[r] = xbuf[r * BLK + pt];
            }
            __syncthreads();
        }
        if (entf[gb + 1]) {          // (10,9): control wave bit6, target lane bit5
            if (tid & 64) {
                #pragma unroll
                for (int r = 0; r < R; ++r) v[r] = shx(v[r], 32);
            }
        }
        if (entf[gb + 2]) cnot_ll<32, 16>(v, tid);   // (9,8)
        if (entf[gb + 3]) cnot_ll<16,  8>(v, tid);   // (8,7)
        if (entf[gb + 4]) cnot_ll< 8,  4>(v, tid);   // (7,6)
        if (entf[gb + 5]) cnot_ll< 4,  2>(v, tid);   // (6,5)
        if (entf[gb + 6]) cnot_ll< 2,  1>(v, tid);   // (5,4)
        if (entf[gb + 7]) {          // (4,3): control lane bit0, target reg bit3
            const bool c_ = tid & 1;
            #pragma unroll
            for (int r = 0; r < 8; ++r) {
                c32 a = v[r], bb = v[r | 8];
                v[r]     = c_ ? bb : a;
                v[r | 8] = c_ ? a  : bb;
            }
        }
        if (entf[gb + 8])  cnot_rr<3, 2>(v);         // (3,2)
        if (entf[gb + 9])  cnot_rr<2, 1>(v);         // (2,1)
        if (entf[gb + 10]) cnot_rr<1, 0>(v);         // (1,0)
        if (entf[gb + 11]) {         // (0,11): control reg bit0, target wave bit7
            #pragma unroll
            for (int r = 1; r < R; r += 2) xbuf[(r >> 1) * BLK + tid] = v[r];
            __syncthreads();
            const int pt = tid ^ 128;
            #pragma unroll
            for (int r = 1; r < R; r += 2) v[r] = xbuf[(r >> 1) * BLK + pt];
            __syncthreads();
        }
    }

    // ---- measurement ----
    float pr[R];
    #pragma unroll
    for (int r = 0; r < R; ++r) pr[r] = v[r].x * v[r].x + v[r].y * v[r].y;
    float S = 0.f;
    #pragma unroll
    for (int r = 0; r < R; ++r) S += pr[r];
    float T[4];
    #pragma unroll
    for (int pb = 0; pb < 4; ++pb) {
        float t = 0.f;
        #pragma unroll
        for (int r = 0; r < R; ++r) t += ((r >> pb) & 1) ? -pr[r] : pr[r];
        T[pb] = t;
    }

    float contrib[NQ];
    #pragma unroll
    for (int q = 0; q < 8; ++q) contrib[q] = ((tid >> (7 - q)) & 1) ? -S : S;
    contrib[8] = T[3]; contrib[9] = T[2]; contrib[10] = T[1]; contrib[11] = T[0];

    #pragma unroll
    for (int off = 32; off; off >>= 1) {
        #pragma unroll
        for (int q = 0; q < NQ; ++q) contrib[q] += __shfl_xor(contrib[q], off, 64);
    }
    if ((tid & 63) == 0) {
        const int wv = tid >> 6;
        #pragma unroll
        for (int q = 0; q < NQ; ++q) redbuf[wv * NQ + q] = contrib[q];
    }
    __syncthreads();
    if (tid < NQ)
        out[b * NQ + tid] = redbuf[tid] + redbuf[NQ + tid] + redbuf[2 * NQ + tid] + redbuf[3 * NQ + tid];
}

extern "C" void kernel_launch(void* const* d_in, const int* in_sizes, int n_in,
                              void* d_out, int out_size, void* d_ws, size_t ws_size,
                              hipStream_t stream) {
    const float* x   = (const float*)d_in[0];  // (B,12)
    const float* w   = (const float*)d_in[1];  // (4,12,3)
    const float* ent = (const float*)d_in[2];  // (4,12)
    float* out = (float*)d_out;
    const int B = in_sizes[0] / NQ;
    qsim_kernel<<<B, BLK, 0, stream>>>(x, w, ent, out);
}

// Round 5
// 80.113 us; speedup vs baseline: 1.6962x; 1.0768x over previous
//
#include <hip/hip_runtime.h>
#include <math.h>

constexpr int NQ  = 12;
constexpr int NS  = 1 << NQ;   // 4096 amplitudes
constexpr int NL  = 4;
constexpr int BLK = 256;
constexpr int R   = 16;        // amplitudes per thread (reg bits = amp bits 0..3)
constexpr float PI_F = 3.14159265358979323846f;

// amp index i = (tid << 4) | r
//   bits 0..3  : register index r
//   bits 4..9  : lane bits (tid bits 0..5)
//   bits 10..11: wave bits (tid bits 6..7)

typedef float2 c32;

__device__ __forceinline__ c32 cmul(c32 a, c32 b) {
    return make_float2(a.x * b.x - a.y * b.y, a.x * b.y + a.y * b.x);
}
__device__ __forceinline__ c32 cmad(c32 a, c32 b, c32 c) {
    return make_float2(fmaf(a.x, b.x, fmaf(-a.y, b.y, c.x)),
                       fmaf(a.x, b.y, fmaf( a.y, b.x, c.y)));
}

// ---------------- VALU lane-exchange primitives (no LDS pipe) ----------------
// Direction convention (verified vs rocPRIM reduce): row_shr:N = lane i <- i-N,
// row_shl:N = lane i <- i+N.
template<int CTRL>
__device__ __forceinline__ float dppmov(float v) {
    return __int_as_float(__builtin_amdgcn_mov_dpp(__float_as_int(v), CTRL, 0xF, 0xF, false));
}
// xor4 within a row of 16:
//   banks 0,2 (lanes bit2=0) need i+4  -> row_shl:4
//   banks 1,3 (lanes bit2=1) need i-4  -> row_shr:4
__device__ __forceinline__ float dppx4(float v) {
    int s = __float_as_int(v);
    int o = __builtin_amdgcn_update_dpp(s, s, 0x104, 0xF, 0x5, false); // row_shl:4 -> banks 0,2
    o     = __builtin_amdgcn_update_dpp(o, s, 0x114, 0xF, 0xA, false); // row_shr:4 -> banks 1,3
    return __int_as_float(o);
}

#if __has_builtin(__builtin_amdgcn_permlane16_swap)
#define HAVE_PL16 1
#endif
#if __has_builtin(__builtin_amdgcn_permlane32_swap)
#define HAVE_PL32 1
#endif

template<int M>
__device__ __forceinline__ float lanex(float v, int tid) {
    if constexpr (M == 1)  return dppmov<0xB1>(v);        // quad_perm [1,0,3,2]
    else if constexpr (M == 2)  return dppmov<0x4E>(v);   // quad_perm [2,3,0,1]
    else if constexpr (M == 4)  return dppx4(v);
    else if constexpr (M == 8)  return dppmov<0x128>(v);  // row_ror:8 == xor8 in row16
    else if constexpr (M == 16) {
#ifdef HAVE_PL16
        auto r = __builtin_amdgcn_permlane16_swap(__float_as_int(v), __float_as_int(v), false, false);
        return __int_as_float((tid & 16) ? r[0] : r[1]);
#else
        return __shfl_xor(v, 16, 64);
#endif
    } else { // M == 32
#ifdef HAVE_PL32
        auto r = __builtin_amdgcn_permlane32_swap(__float_as_int(v), __float_as_int(v), false, false);
        return __int_as_float((tid & 32) ? r[0] : r[1]);
#else
        return __shfl_xor(v, 32, 64);
#endif
    }
}
template<int M>
__device__ __forceinline__ c32 cx(c32 v, int tid) {
    return make_float2(lanex<M>(v.x, tid), lanex<M>(v.y, tid));
}

// ---- single-qubit gate, qubit bit in register index ----
template<int P>
__device__ __forceinline__ void gate_reg(c32* v, c32 U00, c32 U01, c32 U10, c32 U11) {
    #pragma unroll
    for (int r = 0; r < R; ++r)
        if (!(r & (1 << P))) {
            c32 a = v[r], b = v[r | (1 << P)];
            v[r]            = cmad(U01, b, cmul(U00, a));
            v[r | (1 << P)] = cmad(U11, b, cmul(U10, a));
        }
}

// ---- single-qubit gate, qubit bit is a lane bit (VALU exchange) ----
template<int M>
__device__ __forceinline__ void gate_lane(c32* v, int tid, c32 U00, c32 U01, c32 U10, c32 U11) {
    const bool hi = tid & M;
    const c32 Ud = hi ? U11 : U00;
    const c32 Uo = hi ? U10 : U01;
    #pragma unroll
    for (int r = 0; r < R; ++r) {
        c32 o = cx<M>(v[r], tid);
        v[r] = cmad(Uo, o, cmul(Ud, v[r]));
    }
}

// ---- CNOT, control+target both lane bits (VALU) ----
template<int CM, int TM>
__device__ __forceinline__ void cnot_ll(c32* v, int tid) {
    const bool c_ = tid & CM;
    #pragma unroll
    for (int r = 0; r < R; ++r) {
        c32 o = cx<TM>(v[r], tid);
        if (c_) v[r] = o;
    }
}

// ---- CNOT, control+target both register bits ----
template<int PC, int PT>
__device__ __forceinline__ void cnot_rr(c32* v) {
    #pragma unroll
    for (int r = 0; r < R; ++r)
        if ((r & (1 << PC)) && !(r & (1 << PT))) {
            c32 t = v[r]; v[r] = v[r ^ (1 << PT)]; v[r ^ (1 << PT)] = t;
        }
}

__global__ __launch_bounds__(BLK, 1)
void qsim_kernel(const float* __restrict__ x,    // (B,12)
                 const float* __restrict__ w,    // (4,12,3)
                 const float* __restrict__ ent,  // (4,12)
                 float* __restrict__ out)        // (B,12)
{
    __shared__ c32  xbuf[NS];           // 32 KB cross-wave exchange
    __shared__ c32  gmat[NL * NQ][4];   // Rot matrices (block-uniform)
    __shared__ c32  uenc[NQ][2];        // encoding per-qubit 2-vectors
    __shared__ int  entf[NL * NQ];
    __shared__ float redbuf[4 * NQ];

    const int tid = threadIdx.x;
    const int b   = blockIdx.x;

    // ---- precompute gate matrices (once per block) ----
    if (tid < NL * NQ) {
        float phi = w[tid * 3 + 0], th = w[tid * 3 + 1], om = w[tid * 3 + 2];
        float s, c;   sincosf(0.5f * th, &s, &c);
        float sa, ca; sincosf(0.5f * (phi + om), &sa, &ca);
        float sm, cm; sincosf(0.5f * (phi - om), &sm, &cm);
        gmat[tid][0] = make_float2( c * ca, -c * sa);
        gmat[tid][1] = make_float2(-s * cm, -s * sm);
        gmat[tid][2] = make_float2( s * cm, -s * sm);
        gmat[tid][3] = make_float2( c * ca,  c * sa);
        entf[tid] = ent[tid] > 0.5f;
    }
    if (tid >= 64 && tid < 64 + NQ) {
        int q = tid - 64;
        float xv = x[b * NQ + q];
        float s, c;   sincosf(0.5f * PI_F * xv, &s, &c);
        float zs, zc; sincosf(0.5f * PI_F * xv * xv, &zs, &zc);
        uenc[q][0] = make_float2(c * zc, -c * zs);
        uenc[q][1] = make_float2(s * zc,  s * zs);
    }
    __syncthreads();

    // ---- build encoded product state directly in registers ----
    c32 A = uenc[0][(tid >> 7) & 1];
    #pragma unroll
    for (int q = 1; q < 8; ++q) A = cmul(A, uenc[q][(tid >> (7 - q)) & 1]);
    c32 AP[4], PAB[4];
    #pragma unroll
    for (int j = 0; j < 4; ++j)
        AP[j] = cmul(A, cmul(uenc[8][j >> 1], uenc[9][j & 1]));
    #pragma unroll
    for (int k = 0; k < 4; ++k)
        PAB[k] = cmul(uenc[10][k >> 1], uenc[11][k & 1]);
    c32 v[R];
    #pragma unroll
    for (int r = 0; r < R; ++r) v[r] = cmul(AP[(r >> 2) & 3], PAB[r & 3]);

    const int lane_slot = tid & 63;
    const int g         = tid >> 6;   // quadrant = amp bits (11,10)

    // ---- layers ----
    #pragma unroll 1
    for (int layer = 0; layer < NL; ++layer) {
        const int gb = layer * NQ;

        // ===== fused 4x4 gate on amp bits (11,10) =====
        //   = Rot(bit11) ⊗ Rot(bit10), with
        //   - this layer's CNOT(11,10) folded as a row permutation (commutes
        //     forward past the Rots on bits 9..0), and
        //   - previous layer's CNOT(0,11) folded as a column permutation on
        //     odd-r amplitudes (it was the op immediately before this gate).
        {
            const c32* Ua = gmat[gb + 0];
            const c32* Ub = gmat[gb + 1];
            const int  gp = (entf[gb + 0] && (g & 2)) ? (g ^ 1) : g;  // CNOT(11,10) fold
            const int  ar = (gp >> 1) * 2, br = (gp & 1) * 2;
            c32 rowE[4], rowO[4];
            rowE[0] = cmul(Ua[ar + 0], Ub[br + 0]);
            rowE[1] = cmul(Ua[ar + 0], Ub[br + 1]);
            rowE[2] = cmul(Ua[ar + 1], Ub[br + 0]);
            rowE[3] = cmul(Ua[ar + 1], Ub[br + 1]);
            const bool pf = (layer > 0) && entf[gb - 1];              // prev CNOT(0,11) fold
            #pragma unroll
            for (int j = 0; j < 4; ++j) rowO[j] = pf ? rowE[j ^ 2] : rowE[j];

            #pragma unroll
            for (int r = 0; r < R; ++r) xbuf[r * BLK + tid] = v[r];
            __syncthreads();
            #pragma unroll
            for (int r = 0; r < R; ++r) {
                const c32* rw = (r & 1) ? rowO : rowE;
                c32 acc = cmul(rw[0], xbuf[r * BLK +   0 + lane_slot]);
                acc     = cmad(rw[1], xbuf[r * BLK +  64 + lane_slot], acc);
                acc     = cmad(rw[2], xbuf[r * BLK + 128 + lane_slot], acc);
                acc     = cmad(rw[3], xbuf[r * BLK + 192 + lane_slot], acc);
                v[r] = acc;
            }
            __syncthreads();
        }

        // ===== Rot gates on lane bits (VALU exchanges) and reg bits =====
        { const c32* u = gmat[gb + 2];  gate_lane<32>(v, tid, u[0], u[1], u[2], u[3]); }
        { const c32* u = gmat[gb + 3];  gate_lane<16>(v, tid, u[0], u[1], u[2], u[3]); }
        { const c32* u = gmat[gb + 4];  gate_lane< 8>(v, tid, u[0], u[1], u[2], u[3]); }
        { const c32* u = gmat[gb + 5];  gate_lane< 4>(v, tid, u[0], u[1], u[2], u[3]); }
        { const c32* u = gmat[gb + 6];  gate_lane< 2>(v, tid, u[0], u[1], u[2], u[3]); }
        { const c32* u = gmat[gb + 7];  gate_lane< 1>(v, tid, u[0], u[1], u[2], u[3]); }
        { const c32* u = gmat[gb + 8];  gate_reg<3>(v, u[0], u[1], u[2], u[3]); }
        { const c32* u = gmat[gb + 9];  gate_reg<2>(v, u[0], u[1], u[2], u[3]); }
        { const c32* u = gmat[gb + 10]; gate_reg<1>(v, u[0], u[1], u[2], u[3]); }
        { const c32* u = gmat[gb + 11]; gate_reg<0>(v, u[0], u[1], u[2], u[3]); }

        // ===== CNOT chain (q=0 folded above; q=11 folded into next layer) =====
        if (entf[gb + 1] && (tid & 64)) {      // (10,9): wave-uniform branch
            #pragma unroll
            for (int r = 0; r < R; ++r) v[r] = cx<32>(v[r], tid);
        }
        if (entf[gb + 2]) cnot_ll<32, 16>(v, tid);   // (9,8)
        if (entf[gb + 3]) cnot_ll<16,  8>(v, tid);   // (8,7)
        if (entf[gb + 4]) cnot_ll< 8,  4>(v, tid);   // (7,6)
        if (entf[gb + 5]) cnot_ll< 4,  2>(v, tid);   // (6,5)
        if (entf[gb + 6]) cnot_ll< 2,  1>(v, tid);   // (5,4)
        if (entf[gb + 7]) {                          // (4,3): lane0 control, reg bit3 target
            const bool c_ = tid & 1;
            #pragma unroll
            for (int r = 0; r < 8; ++r) {
                c32 a = v[r], bb = v[r | 8];
                v[r]     = c_ ? bb : a;
                v[r | 8] = c_ ? a  : bb;
            }
        }
        if (entf[gb + 8])  cnot_rr<3, 2>(v);         // (3,2)
        if (entf[gb + 9])  cnot_rr<2, 1>(v);         // (2,1)
        if (entf[gb + 10]) cnot_rr<1, 0>(v);         // (1,0)
    }

    // ===== last layer's CNOT(0,11): no following fused gate, do via LDS =====
    if (entf[(NL - 1) * NQ + 11]) {
        #pragma unroll
        for (int r = 1; r < R; r += 2) xbuf[(r >> 1) * BLK + tid] = v[r];
        __syncthreads();
        const int pt = tid ^ 128;
        #pragma unroll
        for (int r = 1; r < R; r += 2) v[r] = xbuf[(r >> 1) * BLK + pt];
        __syncthreads();
    }

    // ---- measurement ----
    float pr[R];
    #pragma unroll
    for (int r = 0; r < R; ++r) pr[r] = v[r].x * v[r].x + v[r].y * v[r].y;
    float S = 0.f;
    #pragma unroll
    for (int r = 0; r < R; ++r) S += pr[r];
    float T[4];
    #pragma unroll
    for (int pb = 0; pb < 4; ++pb) {
        float t = 0.f;
        #pragma unroll
        for (int r = 0; r < R; ++r) t += ((r >> pb) & 1) ? -pr[r] : pr[r];
        T[pb] = t;
    }

    float contrib[NQ];
    #pragma unroll
    for (int q = 0; q < 8; ++q) contrib[q] = ((tid >> (7 - q)) & 1) ? -S : S;
    contrib[8] = T[3]; contrib[9] = T[2]; contrib[10] = T[1]; contrib[11] = T[0];

    #pragma unroll
    for (int off = 32; off; off >>= 1) {
        #pragma unroll
        for (int q = 0; q < NQ; ++q) contrib[q] += __shfl_xor(contrib[q], off, 64);
    }
    if ((tid & 63) == 0) {
        const int wv = tid >> 6;
        #pragma unroll
        for (int q = 0; q < NQ; ++q) redbuf[wv * NQ + q] = contrib[q];
    }
    __syncthreads();
    if (tid < NQ)
        out[b * NQ + tid] = redbuf[tid] + redbuf[NQ + tid] + redbuf[2 * NQ + tid] + redbuf[3 * NQ + tid];
}

extern "C" void kernel_launch(void* const* d_in, const int* in_sizes, int n_in,
                              void* d_out, int out_size, void* d_ws, size_t ws_size,
                              hipStream_t stream) {
    const float* x   = (const float*)d_in[0];  // (B,12)
    const float* w   = (const float*)d_in[1];  // (4,12,3)
    const float* ent = (const float*)d_in[2];  // (4,12)
    float* out = (float*)d_out;
    const int B = in_sizes[0] / NQ;
    qsim_kernel<<<B, BLK, 0, stream>>>(x, w, ent, out);
}